// Round 1
// baseline (192.705 us; speedup 1.0000x reference)
//
#include <hip/hip_runtime.h>

// GAT layer (2 heads, N=100k, D=64, E=1.7M), fp32.
// Pipeline (no global atomics anywhere):
//   k_cast_hist   : FUSED: blocks [0,NT) per-tile bucket counts (u16);
//                   blocks [NT,..) per-node scores (4 dots) + bf16 cast of x
//   k_col_scan    : per-bucket exclusive prefix over tiles -> tbase, totals -> bcnt
//   k_binning     : deterministic LDS counting-sort of each tile into bucket runs
//                   (rescans bcnt in LDS -> bucket bases; no separate bucket_scan)
//   k_rowsort     : per-bucket row sort (1024 thr), XCD-local scatter
//   k_gather      : per-node wave gather, bf16 x, 8 lanes/row dwordx4
//                   -> 8 edges per 1KB load instr
// out[i,:] = sum_e coef[e]*x[col[e],:], coef = 0.5*(e0/rs0 + e1/rs1).
// bf16 gather safe: convex combination per head -> err <= max|x|*2^-9 << 0.037.
// NOTE: xh MUST be 128B-aligned: R4 regression (FETCH 119->215MB) was xh at
// offset % 128 == 16 -> every 128B row gather straddled an extra cache line.

#define D 64
#define ALPHA 0.2f
#define CAP 96          // LDS stash per node in k_gather (multiple of 8)
#define BSHIFT 9        // rows per bucket = 512
#define BROWS 512
#define MAXBUK 256      // supports N <= 131072
#define TILE 2048       // edges per binning tile
#define PACKSHIFT 23    // pack = (row & 511) << 23 | col  (col < 2^23)
#define COLMASK ((1u << PACKSHIFT) - 1u)

__device__ __forceinline__ unsigned bf16rne(float f) {
    unsigned u = __float_as_uint(f);
    u += 0x7fffu + ((u >> 16) & 1u);   // round-to-nearest-even
    return u >> 16;
}

// fused: blocks [0,NT) = tile histogram (feeds critical path);
//        blocks [NT,..) = one wave per node: bf16 cast + 4 length-64 dots
__global__ __launch_bounds__(256) void k_cast_hist(
    const float* __restrict__ x, const float* __restrict__ W,
    const float* __restrict__ a, float2* __restrict__ ssrc,
    float2* __restrict__ sdst, unsigned short* __restrict__ xh, int N,
    const int* __restrict__ row, unsigned short* __restrict__ tcnt,
    int E, int nbuk, int NT)
{
    if ((int)blockIdx.x < NT) {
        __shared__ int h[MAXBUK];
        int t = threadIdx.x, base = blockIdx.x * TILE;
        int cnt = E - base; if (cnt > TILE) cnt = TILE;
        for (int i = t; i < nbuk; i += 256) h[i] = 0;
        __syncthreads();
        for (int i = t; i < cnt; i += 256) atomicAdd(&h[row[base + i] >> BSHIFT], 1);
        __syncthreads();
        for (int i = t; i < nbuk; i += 256)
            tcnt[(size_t)blockIdx.x * MAXBUK + i] = (unsigned short)h[i];
        return;
    }
    int wid  = (blockIdx.x - NT) * 4 + (threadIdx.x >> 6);
    int lane = threadIdx.x & 63;
    if (wid >= N) return;
    float v = x[(size_t)wid * D + lane];
    xh[(size_t)wid * D + lane] = (unsigned short)bf16rne(v);
    float h0 = v * W[lane];
    float h1 = v * W[D + lane];
    float t0 = h0 * a[lane];          // src head0
    float t1 = h0 * a[D + lane];      // dst head0
    float t2 = h1 * a[2 * D + lane];  // src head1
    float t3 = h1 * a[3 * D + lane];  // dst head1
#pragma unroll
    for (int off = 32; off; off >>= 1) {
        t0 += __shfl_xor(t0, off);
        t1 += __shfl_xor(t1, off);
        t2 += __shfl_xor(t2, off);
        t3 += __shfl_xor(t3, off);
    }
    if (lane == 0) { ssrc[wid] = make_float2(t0, t2); sdst[wid] = make_float2(t1, t3); }
}

// one block per bucket: exclusive prefix of tcnt[:,b] over tiles (NT <= 1024)
__global__ __launch_bounds__(256) void k_col_scan(
    const unsigned short* __restrict__ tcnt, int* __restrict__ tbase,
    int* __restrict__ bcnt, int NT, int nbuk)
{
    __shared__ int wsum[256];
    int b = blockIdx.x, t = threadIdx.x;
    int t4 = t * 4;
    int v0 = (t4     < NT) ? tcnt[(size_t)(t4    ) * MAXBUK + b] : 0;
    int v1 = (t4 + 1 < NT) ? tcnt[(size_t)(t4 + 1) * MAXBUK + b] : 0;
    int v2 = (t4 + 2 < NT) ? tcnt[(size_t)(t4 + 2) * MAXBUK + b] : 0;
    int v3 = (t4 + 3 < NT) ? tcnt[(size_t)(t4 + 3) * MAXBUK + b] : 0;
    int sv = v0 + v1 + v2 + v3;
    wsum[t] = sv;
    __syncthreads();
    for (int off = 1; off < 256; off <<= 1) {
        int add = (t >= off) ? wsum[t - off] : 0;
        __syncthreads();
        wsum[t] += add;
        __syncthreads();
    }
    int run = wsum[t] - sv;
    if (t4     < NT) { tbase[(t4    ) * MAXBUK + b] = run; run += v0; }
    if (t4 + 1 < NT) { tbase[(t4 + 1) * MAXBUK + b] = run; run += v1; }
    if (t4 + 2 < NT) { tbase[(t4 + 2) * MAXBUK + b] = run; run += v2; }
    if (t4 + 3 < NT) { tbase[(t4 + 3) * MAXBUK + b] = run; run += v3; }
    if (t == 255) bcnt[b] = wsum[255];
}

// deterministic tile binning: LDS counting sort, run-coalesced bucket appends.
// recomputes bucket bases from bcnt in LDS (scanned alongside the tile scan).
__global__ __launch_bounds__(256) void k_binning(
    const int* __restrict__ row, const int* __restrict__ col,
    const int* __restrict__ bcnt, const int* __restrict__ tbase,
    unsigned* __restrict__ ebuf, int E, int nbuk)
{
    __shared__ int lrow[TILE];
    __shared__ int lcol[TILE];
    __shared__ int h[MAXBUK];    // per-bucket count in this tile
    __shared__ int st[MAXBUK];   // local exclusive start
    __shared__ int gb[MAXBUK];   // deterministic global base
    __shared__ int cur[MAXBUK];  // local placement cursor
    __shared__ int sd[MAXBUK];   // scan temp (tile hist)
    __shared__ int sb[MAXBUK];   // scan temp (bucket totals)
    int t = threadIdx.x;
    int base = blockIdx.x * TILE;
    int cnt = E - base; if (cnt > TILE) cnt = TILE;

    for (int i = t; i < nbuk; i += 256) h[i] = 0;
    __syncthreads();

    int r[8], c[8], b[8];
#pragma unroll
    for (int j = 0; j < 8; j++) {
        int li = j * 256 + t;
        if (li < cnt) {
            int idx = base + li;
            r[j] = row[idx]; c[j] = col[idx]; b[j] = r[j] >> BSHIFT;
            atomicAdd(&h[b[j]], 1);
        } else b[j] = -1;
    }
    __syncthreads();

    int bv = (t < nbuk) ? bcnt[t] : 0;
    sd[t] = (t < nbuk) ? h[t] : 0;
    sb[t] = bv;
    __syncthreads();
    for (int off = 1; off < MAXBUK; off <<= 1) {
        int add  = (t >= off) ? sd[t - off] : 0;
        int add2 = (t >= off) ? sb[t - off] : 0;
        __syncthreads();
        sd[t] += add;
        sb[t] += add2;
        __syncthreads();
    }
    if (t < nbuk) {
        int start = sd[t] - h[t];
        st[t]  = start;
        cur[t] = start;
        gb[t]  = (sb[t] - bv) + tbase[blockIdx.x * MAXBUK + t];
    }
    __syncthreads();

#pragma unroll
    for (int j = 0; j < 8; j++) {
        if (b[j] >= 0) {
            int p = atomicAdd(&cur[b[j]], 1);
            lrow[p] = r[j]; lcol[p] = c[j];
        }
    }
    __syncthreads();

    for (int i = t; i < cnt; i += 256) {
        int rr = lrow[i];
        int bb = rr >> BSHIFT;
        ebuf[gb[bb] + (i - st[bb])] =
            ((unsigned)(rr & (BROWS - 1)) << PACKSHIFT) | (unsigned)lcol[i];
    }
}

// one block per bucket (1024 thr = 16 waves): row sort, L2-local scatter.
// recomputes bucket range [s0,s1) from a 256-entry LDS scan of bcnt.
__global__ __launch_bounds__(1024) void k_rowsort(
    const unsigned* __restrict__ ebuf, const int* __restrict__ bcnt,
    int* __restrict__ offsets, int* __restrict__ counts,
    int* __restrict__ scol, int N, int nbuk)
{
    __shared__ int hist[BROWS];
    __shared__ int offs[BROWS];
    __shared__ int wsum[256];
    __shared__ int bsc[MAXBUK];
    int b = blockIdx.x, t = threadIdx.x;
    int lo = b << BSHIFT;

    if (t < MAXBUK) bsc[t] = (t < nbuk) ? bcnt[t] : 0;
    if (t < BROWS) hist[t] = 0;
    __syncthreads();
    for (int off = 1; off < MAXBUK; off <<= 1) {
        int add = (t < MAXBUK && t >= off) ? bsc[t - off] : 0;
        __syncthreads();
        if (t < MAXBUK) bsc[t] += add;
        __syncthreads();
    }
    int s1 = bsc[b];              // inclusive prefix
    int s0 = s1 - bcnt[b];        // exclusive

    for (int i = s0 + t; i < s1; i += 1024)
        atomicAdd(&hist[ebuf[i] >> PACKSHIFT], 1);
    __syncthreads();

    int a0 = 0, a1 = 0, sv = 0;
    if (t < 256) { a0 = hist[2 * t]; a1 = hist[2 * t + 1]; sv = a0 + a1; wsum[t] = sv; }
    __syncthreads();
    for (int off = 1; off < 256; off <<= 1) {
        int add = 0;
        if (t < 256 && t >= off) add = wsum[t - off];
        __syncthreads();
        if (t < 256) wsum[t] += add;
        __syncthreads();
    }
    if (t < 256) { int run = wsum[t] - sv; offs[2 * t] = run; offs[2 * t + 1] = run + a0; }
    __syncthreads();

    if (t < BROWS) {
        int rg = lo + t;
        if (rg < N) { offsets[rg] = s0 + offs[t]; counts[rg] = hist[t]; }
    }
    __syncthreads();
    if (t < BROWS) hist[t] = offs[t];   // hist -> cursor
    __syncthreads();

    for (int i = s0 + t; i < s1; i += 1024) {
        unsigned pk = ebuf[i];
        int p = atomicAdd(&hist[pk >> PACKSHIFT], 1);
        scol[s0 + p] = (int)(pk & COLMASK);
    }
}

// 4 nodes/block, 1 wave/node. Phase 1: lane-parallel e-values + rowsums,
// stash (col, e0, e1). Phase 1.5: precombine coef into (col,coef) float2.
// Phase 2: 8 lane-groups of 8; group e takes edge k+e, lane fi loads dwordx4
// (features 8fi..8fi+7) -> 8 edges per 1KB load instr; one broadcast
// ds_read_b64 + 8 FMA per lane-group per edge.
__global__ __launch_bounds__(256) void k_gather(
    const uint4* __restrict__ xh4, const float2* __restrict__ ssrc,
    const float2* __restrict__ sdst,
    const int* __restrict__ offsets, const int* __restrict__ counts,
    const int* __restrict__ scol, float* __restrict__ out, int N)
{
    __shared__ float  le0[4][CAP];
    __shared__ float  le1[4][CAP];
    __shared__ float2 lpair[4][CAP];   // .x = bitcast col, .y = coef
    int w    = threadIdx.x >> 6;
    int lane = threadIdx.x & 63;
    int n    = blockIdx.x * 4 + w;
    bool valid = (n < N);
    int start = 0, cnt = 0;
    float2 srow = make_float2(0.f, 0.f);
    if (valid) { start = offsets[n]; cnt = counts[n]; srow = ssrc[n]; }

    float sum0 = 0.f, sum1 = 0.f;
    for (int k = lane; k < cnt; k += 64) {
        int c = scol[start + k];
        float2 sd = sdst[c];
        float sc0 = srow.x + sd.x;
        float sc1 = srow.y + sd.y;
        float e0 = __expf(sc0 > 0.f ? sc0 : ALPHA * sc0);
        float e1 = __expf(sc1 > 0.f ? sc1 : ALPHA * sc1);
        sum0 += e0; sum1 += e1;
        if (k < CAP) { lpair[w][k].x = __int_as_float(c); le0[w][k] = e0; le1[w][k] = e1; }
    }
    int m  = cnt < CAP ? cnt : CAP;
    int mp = (m + 7) & ~7;          // zero-pad stash to multiple of 8
    {
        int k = m + lane;
        if (k < mp) { lpair[w][k].x = __int_as_float(0); le0[w][k] = 0.f; le1[w][k] = 0.f; }
    }
#pragma unroll
    for (int off = 32; off; off >>= 1) {
        sum0 += __shfl_xor(sum0, off);
        sum1 += __shfl_xor(sum1, off);
    }
    if (!valid) return;
    float inv0 = 0.5f / sum0, inv1 = 0.5f / sum1;
    for (int k = lane; k < mp; k += 64)     // phase 1.5: precombined coef
        lpair[w][k].y = inv0 * le0[w][k] + inv1 * le1[w][k];
    // all stash arrays are wave-private ([w] slice) -> no barrier needed

    int e  = lane >> 3;        // edge sub-slot 0..7
    int fi = lane & 7;         // feature-octet index: features 8fi..8fi+7
    float a0 = 0.f, a1 = 0.f, a2 = 0.f, a3 = 0.f;
    float a4 = 0.f, a5 = 0.f, a6 = 0.f, a7 = 0.f;
    for (int k = 0; k < mp; k += 8) {
        float2 pr = lpair[w][k + e];
        int c = __float_as_int(pr.x);
        uint4 u = xh4[((unsigned)c << 3) + fi];
        float cf = pr.y;
        a0 += cf * __uint_as_float(u.x << 16);
        a1 += cf * __uint_as_float(u.x & 0xffff0000u);
        a2 += cf * __uint_as_float(u.y << 16);
        a3 += cf * __uint_as_float(u.y & 0xffff0000u);
        a4 += cf * __uint_as_float(u.z << 16);
        a5 += cf * __uint_as_float(u.z & 0xffff0000u);
        a6 += cf * __uint_as_float(u.w << 16);
        a7 += cf * __uint_as_float(u.w & 0xffff0000u);
    }
    for (int kk = CAP + e; kk < cnt; kk += 8) {  // overflow (degree > CAP)
        int c = scol[start + kk];
        float2 sd = sdst[c];
        float sc0 = srow.x + sd.x, sc1 = srow.y + sd.y;
        float coef = inv0 * __expf(sc0 > 0.f ? sc0 : ALPHA * sc0)
                   + inv1 * __expf(sc1 > 0.f ? sc1 : ALPHA * sc1);
        uint4 u = xh4[((unsigned)c << 3) + fi];
        a0 += coef * __uint_as_float(u.x << 16);
        a1 += coef * __uint_as_float(u.x & 0xffff0000u);
        a2 += coef * __uint_as_float(u.y << 16);
        a3 += coef * __uint_as_float(u.y & 0xffff0000u);
        a4 += coef * __uint_as_float(u.z << 16);
        a5 += coef * __uint_as_float(u.z & 0xffff0000u);
        a6 += coef * __uint_as_float(u.w << 16);
        a7 += coef * __uint_as_float(u.w & 0xffff0000u);
    }
#pragma unroll
    for (int off = 8; off < 64; off <<= 1) {
        a0 += __shfl_xor(a0, off); a1 += __shfl_xor(a1, off);
        a2 += __shfl_xor(a2, off); a3 += __shfl_xor(a3, off);
        a4 += __shfl_xor(a4, off); a5 += __shfl_xor(a5, off);
        a6 += __shfl_xor(a6, off); a7 += __shfl_xor(a7, off);
    }
    if (e == 0) {
        float4* o = (float4*)(out + (size_t)n * D + (fi << 3));
        o[0] = make_float4(a0, a1, a2, a3);
        o[1] = make_float4(a4, a5, a6, a7);
    }
}

extern "C" void kernel_launch(void* const* d_in, const int* in_sizes, int n_in,
                              void* d_out, int out_size, void* d_ws, size_t ws_size,
                              hipStream_t stream)
{
    const float* x  = (const float*)d_in[0];
    const int*   ei = (const int*)d_in[1];
    const float* W  = (const float*)d_in[2];
    const float* a  = (const float*)d_in[3];
    float*       out = (float*)d_out;
    int N = in_sizes[0] / D;
    int E = in_sizes[1] / 2;
    const int* row = ei;
    const int* col = ei + E;

    int NBUK = (N + BROWS - 1) >> BSHIFT;   // 196 for N=100000 (<= MAXBUK)
    int NT   = (E + TILE - 1) / TILE;       // 831 for E=1.7M (<= 1024)

    // workspace layout: every array 256B-aligned (xh row alignment is critical)
    uintptr_t wp = (uintptr_t)d_ws;
    auto alloc = [&wp](size_t bytes) -> void* {
        wp = (wp + 255) & ~(uintptr_t)255;
        void* p = (void*)wp;
        wp += bytes;
        return p;
    };
    unsigned short* xh      = (unsigned short*)alloc((size_t)N * D * 2);
    float2*         ssrc    = (float2*)alloc((size_t)N * sizeof(float2));
    float2*         sdst    = (float2*)alloc((size_t)N * sizeof(float2));
    int*            offsets = (int*)alloc((size_t)N * sizeof(int));
    int*            counts  = (int*)alloc((size_t)N * sizeof(int));
    int*            scol    = (int*)alloc((size_t)E * sizeof(int));
    unsigned*       ebuf    = (unsigned*)alloc((size_t)E * sizeof(unsigned));
    int*            tbase   = (int*)alloc((size_t)NT * MAXBUK * sizeof(int));
    int*            bcnt    = (int*)alloc(MAXBUK * sizeof(int));
    unsigned short* tcnt    = (unsigned short*)alloc((size_t)NT * MAXBUK * 2);

    int grid_ch = NT + (N + 3) / 4;
    k_cast_hist<<<grid_ch, 256, 0, stream>>>(x, W, a, ssrc, sdst, xh, N,
                                             row, tcnt, E, NBUK, NT);
    k_col_scan<<<NBUK, 256, 0, stream>>>(tcnt, tbase, bcnt, NT, NBUK);
    k_binning<<<NT, 256, 0, stream>>>(row, col, bcnt, tbase, ebuf, E, NBUK);
    k_rowsort<<<NBUK, 1024, 0, stream>>>(ebuf, bcnt, offsets, counts, scol, N, NBUK);
    k_gather<<<(N + 3) / 4, 256, 0, stream>>>((const uint4*)xh, ssrc, sdst,
                                              offsets, counts, scol, out, N);
}

// Round 2
// 189.056 us; speedup vs baseline: 1.0193x; 1.0193x over previous
//
#include <hip/hip_runtime.h>

// GAT layer (2 heads, N=100k, D=64, E=1.7M), fp32.
// Pipeline (no global atomics anywhere):
//   k_cast_hist   : FUSED: blocks [0,NT) per-tile bucket counts (u16);
//                   blocks [NT,..) per-node scores (4 dots) + bf16 cast of x
//   k_col_scan    : per-bucket exclusive prefix over tiles -> tbase, totals -> bcnt
//   k_binning     : deterministic LDS counting-sort of each tile into bucket runs
//   k_rowsort     : per-bucket row sort (1024 thr), XCD-local scatter
//   k_gather      : per-node wave gather, bf16 x, 8 lanes/row dwordx4,
//                   ALL loads hoisted before the sum-reduce (4-deep MLP)
// out[i,:] = sum_e coef[e]*x[col[e],:], coef = 0.5*(e0/rs0 + e1/rs1).
// bf16 gather safe: convex combination per head -> err <= max|x|*2^-9 << 0.037.
// NOTE: xh MUST be 128B-aligned: R4 regression (FETCH 119->215MB) was xh at
// offset % 128 == 16 -> every 128B row gather straddled an extra cache line.
// R1 lesson: 1 load per 8-edge iter -> latency-bound (VALU 60%, HBM 27%).
// R2: hoist cols+loads for up to 4 groups before the shuffle reduce.

#define D 64
#define ALPHA 0.2f
#define CAP 96          // LDS stash per node in k_gather (multiple of 8)
#define BSHIFT 9        // rows per bucket = 512
#define BROWS 512
#define MAXBUK 256      // supports N <= 131072
#define TILE 2048       // edges per binning tile
#define PACKSHIFT 23    // pack = (row & 511) << 23 | col  (col < 2^23)
#define COLMASK ((1u << PACKSHIFT) - 1u)

__device__ __forceinline__ unsigned bf16rne(float f) {
    unsigned u = __float_as_uint(f);
    u += 0x7fffu + ((u >> 16) & 1u);   // round-to-nearest-even
    return u >> 16;
}

// fused: blocks [0,NT) = tile histogram (feeds critical path);
//        blocks [NT,..) = one wave per node: bf16 cast + 4 length-64 dots
__global__ __launch_bounds__(256) void k_cast_hist(
    const float* __restrict__ x, const float* __restrict__ W,
    const float* __restrict__ a, float2* __restrict__ ssrc,
    float2* __restrict__ sdst, unsigned short* __restrict__ xh, int N,
    const int* __restrict__ row, unsigned short* __restrict__ tcnt,
    int E, int nbuk, int NT)
{
    if ((int)blockIdx.x < NT) {
        __shared__ int h[MAXBUK];
        int t = threadIdx.x, base = blockIdx.x * TILE;
        int cnt = E - base; if (cnt > TILE) cnt = TILE;
        for (int i = t; i < nbuk; i += 256) h[i] = 0;
        __syncthreads();
        for (int i = t; i < cnt; i += 256) atomicAdd(&h[row[base + i] >> BSHIFT], 1);
        __syncthreads();
        for (int i = t; i < nbuk; i += 256)
            tcnt[(size_t)blockIdx.x * MAXBUK + i] = (unsigned short)h[i];
        return;
    }
    int wid  = (blockIdx.x - NT) * 4 + (threadIdx.x >> 6);
    int lane = threadIdx.x & 63;
    if (wid >= N) return;
    float v = x[(size_t)wid * D + lane];
    xh[(size_t)wid * D + lane] = (unsigned short)bf16rne(v);
    float h0 = v * W[lane];
    float h1 = v * W[D + lane];
    float t0 = h0 * a[lane];          // src head0
    float t1 = h0 * a[D + lane];      // dst head0
    float t2 = h1 * a[2 * D + lane];  // src head1
    float t3 = h1 * a[3 * D + lane];  // dst head1
#pragma unroll
    for (int off = 32; off; off >>= 1) {
        t0 += __shfl_xor(t0, off);
        t1 += __shfl_xor(t1, off);
        t2 += __shfl_xor(t2, off);
        t3 += __shfl_xor(t3, off);
    }
    if (lane == 0) { ssrc[wid] = make_float2(t0, t2); sdst[wid] = make_float2(t1, t3); }
}

// one block per bucket: exclusive prefix of tcnt[:,b] over tiles (NT <= 1024)
__global__ __launch_bounds__(256) void k_col_scan(
    const unsigned short* __restrict__ tcnt, int* __restrict__ tbase,
    int* __restrict__ bcnt, int NT, int nbuk)
{
    __shared__ int wsum[256];
    int b = blockIdx.x, t = threadIdx.x;
    int t4 = t * 4;
    int v0 = (t4     < NT) ? tcnt[(size_t)(t4    ) * MAXBUK + b] : 0;
    int v1 = (t4 + 1 < NT) ? tcnt[(size_t)(t4 + 1) * MAXBUK + b] : 0;
    int v2 = (t4 + 2 < NT) ? tcnt[(size_t)(t4 + 2) * MAXBUK + b] : 0;
    int v3 = (t4 + 3 < NT) ? tcnt[(size_t)(t4 + 3) * MAXBUK + b] : 0;
    int sv = v0 + v1 + v2 + v3;
    wsum[t] = sv;
    __syncthreads();
    for (int off = 1; off < 256; off <<= 1) {
        int add = (t >= off) ? wsum[t - off] : 0;
        __syncthreads();
        wsum[t] += add;
        __syncthreads();
    }
    int run = wsum[t] - sv;
    if (t4     < NT) { tbase[(t4    ) * MAXBUK + b] = run; run += v0; }
    if (t4 + 1 < NT) { tbase[(t4 + 1) * MAXBUK + b] = run; run += v1; }
    if (t4 + 2 < NT) { tbase[(t4 + 2) * MAXBUK + b] = run; run += v2; }
    if (t4 + 3 < NT) { tbase[(t4 + 3) * MAXBUK + b] = run; run += v3; }
    if (t == 255) bcnt[b] = wsum[255];
}

// deterministic tile binning: LDS counting sort, run-coalesced bucket appends.
// recomputes bucket bases from bcnt in LDS (scanned alongside the tile scan).
__global__ __launch_bounds__(256) void k_binning(
    const int* __restrict__ row, const int* __restrict__ col,
    const int* __restrict__ bcnt, const int* __restrict__ tbase,
    unsigned* __restrict__ ebuf, int E, int nbuk)
{
    __shared__ int lrow[TILE];
    __shared__ int lcol[TILE];
    __shared__ int h[MAXBUK];    // per-bucket count in this tile
    __shared__ int st[MAXBUK];   // local exclusive start
    __shared__ int gb[MAXBUK];   // deterministic global base
    __shared__ int cur[MAXBUK];  // local placement cursor
    __shared__ int sd[MAXBUK];   // scan temp (tile hist)
    __shared__ int sb[MAXBUK];   // scan temp (bucket totals)
    int t = threadIdx.x;
    int base = blockIdx.x * TILE;
    int cnt = E - base; if (cnt > TILE) cnt = TILE;

    for (int i = t; i < nbuk; i += 256) h[i] = 0;
    __syncthreads();

    int r[8], c[8], b[8];
#pragma unroll
    for (int j = 0; j < 8; j++) {
        int li = j * 256 + t;
        if (li < cnt) {
            int idx = base + li;
            r[j] = row[idx]; c[j] = col[idx]; b[j] = r[j] >> BSHIFT;
            atomicAdd(&h[b[j]], 1);
        } else b[j] = -1;
    }
    __syncthreads();

    int bv = (t < nbuk) ? bcnt[t] : 0;
    sd[t] = (t < nbuk) ? h[t] : 0;
    sb[t] = bv;
    __syncthreads();
    for (int off = 1; off < MAXBUK; off <<= 1) {
        int add  = (t >= off) ? sd[t - off] : 0;
        int add2 = (t >= off) ? sb[t - off] : 0;
        __syncthreads();
        sd[t] += add;
        sb[t] += add2;
        __syncthreads();
    }
    if (t < nbuk) {
        int start = sd[t] - h[t];
        st[t]  = start;
        cur[t] = start;
        gb[t]  = (sb[t] - bv) + tbase[blockIdx.x * MAXBUK + t];
    }
    __syncthreads();

#pragma unroll
    for (int j = 0; j < 8; j++) {
        if (b[j] >= 0) {
            int p = atomicAdd(&cur[b[j]], 1);
            lrow[p] = r[j]; lcol[p] = c[j];
        }
    }
    __syncthreads();

    for (int i = t; i < cnt; i += 256) {
        int rr = lrow[i];
        int bb = rr >> BSHIFT;
        ebuf[gb[bb] + (i - st[bb])] =
            ((unsigned)(rr & (BROWS - 1)) << PACKSHIFT) | (unsigned)lcol[i];
    }
}

// one block per bucket (1024 thr = 16 waves): row sort, L2-local scatter.
// recomputes bucket range [s0,s1) from a 256-entry LDS scan of bcnt.
__global__ __launch_bounds__(1024) void k_rowsort(
    const unsigned* __restrict__ ebuf, const int* __restrict__ bcnt,
    int* __restrict__ offsets, int* __restrict__ counts,
    int* __restrict__ scol, int N, int nbuk)
{
    __shared__ int hist[BROWS];
    __shared__ int offs[BROWS];
    __shared__ int wsum[256];
    __shared__ int bsc[MAXBUK];
    int b = blockIdx.x, t = threadIdx.x;
    int lo = b << BSHIFT;

    if (t < MAXBUK) bsc[t] = (t < nbuk) ? bcnt[t] : 0;
    if (t < BROWS) hist[t] = 0;
    __syncthreads();
    for (int off = 1; off < MAXBUK; off <<= 1) {
        int add = (t < MAXBUK && t >= off) ? bsc[t - off] : 0;
        __syncthreads();
        if (t < MAXBUK) bsc[t] += add;
        __syncthreads();
    }
    int s1 = bsc[b];              // inclusive prefix
    int s0 = s1 - bcnt[b];        // exclusive

    for (int i = s0 + t; i < s1; i += 1024)
        atomicAdd(&hist[ebuf[i] >> PACKSHIFT], 1);
    __syncthreads();

    int a0 = 0, a1 = 0, sv = 0;
    if (t < 256) { a0 = hist[2 * t]; a1 = hist[2 * t + 1]; sv = a0 + a1; wsum[t] = sv; }
    __syncthreads();
    for (int off = 1; off < 256; off <<= 1) {
        int add = 0;
        if (t < 256 && t >= off) add = wsum[t - off];
        __syncthreads();
        if (t < 256) wsum[t] += add;
        __syncthreads();
    }
    if (t < 256) { int run = wsum[t] - sv; offs[2 * t] = run; offs[2 * t + 1] = run + a0; }
    __syncthreads();

    if (t < BROWS) {
        int rg = lo + t;
        if (rg < N) { offsets[rg] = s0 + offs[t]; counts[rg] = hist[t]; }
    }
    __syncthreads();
    if (t < BROWS) hist[t] = offs[t];   // hist -> cursor
    __syncthreads();

    for (int i = s0 + t; i < s1; i += 1024) {
        unsigned pk = ebuf[i];
        int p = atomicAdd(&hist[pk >> PACKSHIFT], 1);
        scol[s0 + p] = (int)(pk & COLMASK);
    }
}

// unpack 8 bf16 of u (uint4) and accumulate with scalar coef cf
#define ACC8(u, cf)                              \
    a0 += cf * __uint_as_float((u).x << 16);         \
    a1 += cf * __uint_as_float((u).x & 0xffff0000u); \
    a2 += cf * __uint_as_float((u).y << 16);         \
    a3 += cf * __uint_as_float((u).y & 0xffff0000u); \
    a4 += cf * __uint_as_float((u).z << 16);         \
    a5 += cf * __uint_as_float((u).z & 0xffff0000u); \
    a6 += cf * __uint_as_float((u).w << 16);         \
    a7 += cf * __uint_as_float((u).w & 0xffff0000u);

// 4 nodes/block, 1 wave/node. Phase 1: lane-parallel e-values + rowsums,
// stash (col, e0, e1). Phase 2: 8 lane-groups of 8; group e takes edge k+e,
// lane fi loads dwordx4 (features 8fi..8fi+7) -> 8 edges per 1KB load instr.
// MLP: cols are known before the rowsum reduce -> read up to 4 group cols and
// issue all 4 xh4 loads FIRST, hide their latency under the shuffle reduce +
// coef FMAs. nit is wave-uniform -> branches are s_cbranch, no divergence.
__global__ __launch_bounds__(256) void k_gather(
    const uint4* __restrict__ xh4, const float2* __restrict__ ssrc,
    const float2* __restrict__ sdst,
    const int* __restrict__ offsets, const int* __restrict__ counts,
    const int* __restrict__ scol, float* __restrict__ out, int N)
{
    __shared__ int   lcol[4][CAP];
    __shared__ float le0[4][CAP];
    __shared__ float le1[4][CAP];
    int w    = threadIdx.x >> 6;
    int lane = threadIdx.x & 63;
    int n    = blockIdx.x * 4 + w;
    bool valid = (n < N);
    int start = 0, cnt = 0;
    float2 srow = make_float2(0.f, 0.f);
    if (valid) { start = offsets[n]; cnt = counts[n]; srow = ssrc[n]; }

    float sum0 = 0.f, sum1 = 0.f;
    for (int k = lane; k < cnt; k += 64) {
        int c = scol[start + k];
        float2 sd = sdst[c];
        float sc0 = srow.x + sd.x;
        float sc1 = srow.y + sd.y;
        float e0 = __expf(sc0 > 0.f ? sc0 : ALPHA * sc0);
        float e1 = __expf(sc1 > 0.f ? sc1 : ALPHA * sc1);
        sum0 += e0; sum1 += e1;
        if (k < CAP) { lcol[w][k] = c; le0[w][k] = e0; le1[w][k] = e1; }
    }
    int m  = cnt < CAP ? cnt : CAP;
    int mp = (m + 7) & ~7;          // zero-pad stash to multiple of 8
    {
        int k = m + lane;
        if (k < mp) { lcol[w][k] = 0; le0[w][k] = 0.f; le1[w][k] = 0.f; }
    }
    if (!valid) return;   // wave-uniform; stash is wave-private, no barriers

    int e  = lane >> 3;        // edge sub-slot 0..7
    int fi = lane & 7;         // feature-octet index: features 8fi..8fi+7
    int nit = mp >> 3;         // 8-edge groups (1..12); <=4 covers cnt<=32

    // ---- hoist: read group cols, issue ALL global loads up-front ----
    int c0 = lcol[w][e], c1 = 0, c2 = 0, c3 = 0;
    if (nit > 1) c1 = lcol[w][ 8 + e];
    if (nit > 2) c2 = lcol[w][16 + e];
    if (nit > 3) c3 = lcol[w][24 + e];
    uint4 u0 = xh4[((unsigned)c0 << 3) + fi];
    uint4 u1 = make_uint4(0, 0, 0, 0), u2 = u1, u3 = u1;
    if (nit > 1) u1 = xh4[((unsigned)c1 << 3) + fi];
    if (nit > 2) u2 = xh4[((unsigned)c2 << 3) + fi];
    if (nit > 3) u3 = xh4[((unsigned)c3 << 3) + fi];

    // ---- latency of the 4 loads hides under this reduce + coef math ----
#pragma unroll
    for (int off = 32; off; off >>= 1) {
        sum0 += __shfl_xor(sum0, off);
        sum1 += __shfl_xor(sum1, off);
    }
    float inv0 = 0.5f / sum0, inv1 = 0.5f / sum1;
    float cf0 = inv0 * le0[w][e] + inv1 * le1[w][e];
    float cf1 = 0.f, cf2 = 0.f, cf3 = 0.f;
    if (nit > 1) cf1 = inv0 * le0[w][ 8 + e] + inv1 * le1[w][ 8 + e];
    if (nit > 2) cf2 = inv0 * le0[w][16 + e] + inv1 * le1[w][16 + e];
    if (nit > 3) cf3 = inv0 * le0[w][24 + e] + inv1 * le1[w][24 + e];

    float a0 = 0.f, a1 = 0.f, a2 = 0.f, a3 = 0.f;
    float a4 = 0.f, a5 = 0.f, a6 = 0.f, a7 = 0.f;
    ACC8(u0, cf0)
    if (nit > 1) { ACC8(u1, cf1) }
    if (nit > 2) { ACC8(u2, cf2) }
    if (nit > 3) { ACC8(u3, cf3) }

    for (int k = 32; k < mp; k += 8) {       // rare: cnt > 32
        int c = lcol[w][k + e];
        float cf = inv0 * le0[w][k + e] + inv1 * le1[w][k + e];
        uint4 u = xh4[((unsigned)c << 3) + fi];
        ACC8(u, cf)
    }
    for (int kk = CAP + e; kk < cnt; kk += 8) {  // overflow (degree > CAP)
        int c = scol[start + kk];
        float2 sd = sdst[c];
        float sc0 = srow.x + sd.x, sc1 = srow.y + sd.y;
        float coef = inv0 * __expf(sc0 > 0.f ? sc0 : ALPHA * sc0)
                   + inv1 * __expf(sc1 > 0.f ? sc1 : ALPHA * sc1);
        uint4 u = xh4[((unsigned)c << 3) + fi];
        ACC8(u, coef)
    }
#pragma unroll
    for (int off = 8; off < 64; off <<= 1) {
        a0 += __shfl_xor(a0, off); a1 += __shfl_xor(a1, off);
        a2 += __shfl_xor(a2, off); a3 += __shfl_xor(a3, off);
        a4 += __shfl_xor(a4, off); a5 += __shfl_xor(a5, off);
        a6 += __shfl_xor(a6, off); a7 += __shfl_xor(a7, off);
    }
    if (e == 0) {
        float4* o = (float4*)(out + (size_t)n * D + (fi << 3));
        o[0] = make_float4(a0, a1, a2, a3);
        o[1] = make_float4(a4, a5, a6, a7);
    }
}

extern "C" void kernel_launch(void* const* d_in, const int* in_sizes, int n_in,
                              void* d_out, int out_size, void* d_ws, size_t ws_size,
                              hipStream_t stream)
{
    const float* x  = (const float*)d_in[0];
    const int*   ei = (const int*)d_in[1];
    const float* W  = (const float*)d_in[2];
    const float* a  = (const float*)d_in[3];
    float*       out = (float*)d_out;
    int N = in_sizes[0] / D;
    int E = in_sizes[1] / 2;
    const int* row = ei;
    const int* col = ei + E;

    int NBUK = (N + BROWS - 1) >> BSHIFT;   // 196 for N=100000 (<= MAXBUK)
    int NT   = (E + TILE - 1) / TILE;       // 831 for E=1.7M (<= 1024)

    // workspace layout: every array 256B-aligned (xh row alignment is critical)
    uintptr_t wp = (uintptr_t)d_ws;
    auto alloc = [&wp](size_t bytes) -> void* {
        wp = (wp + 255) & ~(uintptr_t)255;
        void* p = (void*)wp;
        wp += bytes;
        return p;
    };
    unsigned short* xh      = (unsigned short*)alloc((size_t)N * D * 2);
    float2*         ssrc    = (float2*)alloc((size_t)N * sizeof(float2));
    float2*         sdst    = (float2*)alloc((size_t)N * sizeof(float2));
    int*            offsets = (int*)alloc((size_t)N * sizeof(int));
    int*            counts  = (int*)alloc((size_t)N * sizeof(int));
    int*            scol    = (int*)alloc((size_t)E * sizeof(int));
    unsigned*       ebuf    = (unsigned*)alloc((size_t)E * sizeof(unsigned));
    int*            tbase   = (int*)alloc((size_t)NT * MAXBUK * sizeof(int));
    int*            bcnt    = (int*)alloc(MAXBUK * sizeof(int));
    unsigned short* tcnt    = (unsigned short*)alloc((size_t)NT * MAXBUK * 2);

    int grid_ch = NT + (N + 3) / 4;
    k_cast_hist<<<grid_ch, 256, 0, stream>>>(x, W, a, ssrc, sdst, xh, N,
                                             row, tcnt, E, NBUK, NT);
    k_col_scan<<<NBUK, 256, 0, stream>>>(tcnt, tbase, bcnt, NT, NBUK);
    k_binning<<<NT, 256, 0, stream>>>(row, col, bcnt, tbase, ebuf, E, NBUK);
    k_rowsort<<<NBUK, 1024, 0, stream>>>(ebuf, bcnt, offsets, counts, scol, N, NBUK);
    k_gather<<<(N + 3) / 4, 256, 0, stream>>>((const uint4*)xh, ssrc, sdst,
                                              offsets, counts, scol, out, N);
}